// Round 2
// baseline (190.077 us; speedup 1.0000x reference)
//
#include <hip/hip_runtime.h>

#define D 128
#define TM 32

// Phase 1: agg[node] = dst_norm[node] * sum_{e in [ptr[node],ptr[node+1])} src_norm[s]*X[s]
// 32 lanes per node, float4 per lane (128 features).
__global__ __launch_bounds__(256) void agg_kernel(
    const int* __restrict__ edge_ptr, const int* __restrict__ src_edges,
    const float* __restrict__ src_norm, const float* __restrict__ dst_norm,
    const float* __restrict__ X, float* __restrict__ agg, int n_nodes) {
  int gid = blockIdx.x * 256 + threadIdx.x;
  int node = gid >> 5;
  if (node >= n_nodes) return;
  int fo = (gid & 31) << 2;  // feature offset (float4)
  int e0 = edge_ptr[node];
  int e1 = edge_ptr[node + 1];
  float ax = 0.f, ay = 0.f, az = 0.f, aw = 0.f;
  for (int e = e0; e < e1; ++e) {
    int s = src_edges[e];
    float ns = src_norm[s];
    float4 v = *reinterpret_cast<const float4*>(X + (size_t)s * D + fo);
    ax = fmaf(ns, v.x, ax);
    ay = fmaf(ns, v.y, ay);
    az = fmaf(ns, v.z, az);
    aw = fmaf(ns, v.w, aw);
  }
  float nd = dst_norm[node];
  float4 r = make_float4(ax * nd, ay * nd, az * nd, aw * nd);
  *reinterpret_cast<float4*>(agg + (size_t)node * D + fo) = r;
}

#define FMA4(acc, sv, wv)            \
  acc.x = fmaf(sv, wv.x, acc.x);     \
  acc.y = fmaf(sv, wv.y, acc.y);     \
  acc.z = fmaf(sv, wv.z, acc.z);     \
  acc.w = fmaf(sv, wv.w, acc.w);

// Phase 2 (in place): io[r,:] = io[r,:] @ W for a TM-row tile per block.
// W (64 KB) + A-tile (16 KB) in LDS. 256 threads: 8 row-groups x 32 col-groups,
// each thread computes 4 rows x 4 cols.
__global__ __launch_bounds__(256) void gemm_kernel(
    float* __restrict__ io, const float* __restrict__ W, int n_rows) {
  __shared__ float Wl[D][D];
  __shared__ float Al[TM][D];
  int tid = threadIdx.x;
  for (int i = tid * 4; i < D * D; i += 1024) {
    *reinterpret_cast<float4*>(&Wl[0][0] + i) =
        *reinterpret_cast<const float4*>(W + i);
  }
  int row0 = blockIdx.x * TM;
  for (int i = tid * 4; i < TM * D; i += 1024) {
    int r = i >> 7, c = i & (D - 1);
    if (row0 + r < n_rows)
      *reinterpret_cast<float4*>(&Al[r][c]) =
          *reinterpret_cast<const float4*>(io + (size_t)(row0 + r) * D + c);
  }
  __syncthreads();

  int cg = (tid & 31) * 4;   // 4 output cols
  int rb = (tid >> 5) * 4;   // 4 output rows
  float4 acc0 = {0, 0, 0, 0}, acc1 = {0, 0, 0, 0};
  float4 acc2 = {0, 0, 0, 0}, acc3 = {0, 0, 0, 0};

#pragma unroll 4
  for (int k = 0; k < D; k += 4) {
    float4 w0 = *reinterpret_cast<const float4*>(&Wl[k + 0][cg]);
    float4 w1 = *reinterpret_cast<const float4*>(&Wl[k + 1][cg]);
    float4 w2 = *reinterpret_cast<const float4*>(&Wl[k + 2][cg]);
    float4 w3 = *reinterpret_cast<const float4*>(&Wl[k + 3][cg]);
    float4 a0 = *reinterpret_cast<const float4*>(&Al[rb + 0][k]);
    float4 a1 = *reinterpret_cast<const float4*>(&Al[rb + 1][k]);
    float4 a2 = *reinterpret_cast<const float4*>(&Al[rb + 2][k]);
    float4 a3 = *reinterpret_cast<const float4*>(&Al[rb + 3][k]);
    FMA4(acc0, a0.x, w0); FMA4(acc0, a0.y, w1); FMA4(acc0, a0.z, w2); FMA4(acc0, a0.w, w3);
    FMA4(acc1, a1.x, w0); FMA4(acc1, a1.y, w1); FMA4(acc1, a1.z, w2); FMA4(acc1, a1.w, w3);
    FMA4(acc2, a2.x, w0); FMA4(acc2, a2.y, w1); FMA4(acc2, a2.z, w2); FMA4(acc2, a2.w, w3);
    FMA4(acc3, a3.x, w0); FMA4(acc3, a3.y, w1); FMA4(acc3, a3.z, w2); FMA4(acc3, a3.w, w3);
  }

  int r0 = row0 + rb;
  if (r0 + 0 < n_rows) *reinterpret_cast<float4*>(io + (size_t)(r0 + 0) * D + cg) = acc0;
  if (r0 + 1 < n_rows) *reinterpret_cast<float4*>(io + (size_t)(r0 + 1) * D + cg) = acc1;
  if (r0 + 2 < n_rows) *reinterpret_cast<float4*>(io + (size_t)(r0 + 2) * D + cg) = acc2;
  if (r0 + 3 < n_rows) *reinterpret_cast<float4*>(io + (size_t)(r0 + 3) * D + cg) = acc3;
}

extern "C" void kernel_launch(void* const* d_in, const int* in_sizes, int n_in,
                              void* d_out, int out_size, void* d_ws, size_t ws_size,
                              hipStream_t stream) {
  const int* edge_ptr = (const int*)d_in[0];
  const int* src_edges = (const int*)d_in[1];
  const float* src_norm = (const float*)d_in[2];
  const float* dst_norm = (const float*)d_in[3];
  const float* X = (const float*)d_in[5];
  const float* W = (const float*)d_in[6];
  float* out = (float*)d_out;
  int n_nodes = in_sizes[2];  // src_norm_degs has N elements

  int blocks1 = (n_nodes * 32 + 255) / 256;
  agg_kernel<<<blocks1, 256, 0, stream>>>(edge_ptr, src_edges, src_norm,
                                          dst_norm, X, out, n_nodes);

  int blocks2 = (n_nodes + TM - 1) / TM;
  gemm_kernel<<<blocks2, 256, 0, stream>>>(out, W, n_nodes);
}

// Round 3
// 90.534 us; speedup vs baseline: 2.0995x; 2.0995x over previous
//
#include <hip/hip_runtime.h>
#include <hip/hip_bf16.h>

#define D 128
#define TM 32
#define PAD 8

typedef unsigned int u32;
typedef unsigned short u16;
typedef __attribute__((ext_vector_type(8))) short short8;
typedef __attribute__((ext_vector_type(4))) float f32x4;

static __device__ __forceinline__ u16 f2b(float x) {
  __hip_bfloat16 b = __float2bfloat16(x);
  return *reinterpret_cast<u16*>(&b);
}
static __device__ __forceinline__ float u2f(u32 x) { return __uint_as_float(x); }

// ---------- bf16 fast path ----------

// Xb[i,j] = bf16(X[i,j] * src_norm[i])  (one float4 -> ushort4 per thread)
__global__ __launch_bounds__(256) void cvt_x(const float* __restrict__ X,
                                             const float* __restrict__ sn,
                                             u16* __restrict__ Xb, int total4) {
  int i = blockIdx.x * 256 + threadIdx.x;
  if (i >= total4) return;
  int row = i >> 5;  // D/4 = 32 float4 per row
  float ns = sn[row];
  float4 v = reinterpret_cast<const float4*>(X)[i];
  ushort4 o;
  o.x = f2b(v.x * ns); o.y = f2b(v.y * ns);
  o.z = f2b(v.z * ns); o.w = f2b(v.w * ns);
  reinterpret_cast<ushort4*>(Xb)[i] = o;
}

// Wt[c,k] = bf16(W[k,c])
__global__ __launch_bounds__(256) void cvt_w(const float* __restrict__ W,
                                             u16* __restrict__ Wt) {
  int i = blockIdx.x * 256 + threadIdx.x;
  if (i >= D * D) return;
  int k = i >> 7, c = i & (D - 1);
  Wt[c * D + k] = f2b(W[k * D + c]);
}

#define ACC8(r)                                             \
  a0 += u2f(r.x << 16); a1 += u2f(r.x & 0xffff0000u);       \
  a2 += u2f(r.y << 16); a3 += u2f(r.y & 0xffff0000u);       \
  a4 += u2f(r.z << 16); a5 += u2f(r.z & 0xffff0000u);       \
  a6 += u2f(r.w << 16); a7 += u2f(r.w & 0xffff0000u);

// aggb[node,:] = bf16( dst_norm[node] * sum_e Xb[src[e],:] )
// 16 lanes per node, 16B (8 bf16) per lane. 4-way edge unroll for MLP.
__global__ __launch_bounds__(256) void agg_bf16(
    const int* __restrict__ edge_ptr, const int* __restrict__ src_edges,
    const float* __restrict__ dst_norm, const u16* __restrict__ Xb,
    u16* __restrict__ aggb, int n_nodes) {
  int gid = blockIdx.x * 256 + threadIdx.x;
  int node = gid >> 4;
  if (node >= n_nodes) return;
  int fo = (gid & 15) << 3;  // bf16 offset in row
  const u16* base = Xb + fo;
  float a0 = 0, a1 = 0, a2 = 0, a3 = 0, a4 = 0, a5 = 0, a6 = 0, a7 = 0;
  int e0 = edge_ptr[node], e1 = edge_ptr[node + 1];
  int e = e0;
  for (; e + 4 <= e1; e += 4) {
    int s0 = src_edges[e + 0], s1 = src_edges[e + 1];
    int s2 = src_edges[e + 2], s3 = src_edges[e + 3];
    uint4 r0 = *reinterpret_cast<const uint4*>(base + (size_t)s0 * D);
    uint4 r1 = *reinterpret_cast<const uint4*>(base + (size_t)s1 * D);
    uint4 r2 = *reinterpret_cast<const uint4*>(base + (size_t)s2 * D);
    uint4 r3 = *reinterpret_cast<const uint4*>(base + (size_t)s3 * D);
    ACC8(r0); ACC8(r1); ACC8(r2); ACC8(r3);
  }
  for (; e < e1; ++e) {
    int s = src_edges[e];
    uint4 r = *reinterpret_cast<const uint4*>(base + (size_t)s * D);
    ACC8(r);
  }
  float nd = dst_norm[node];
  uint4 o;
  o.x = (u32)f2b(a0 * nd) | ((u32)f2b(a1 * nd) << 16);
  o.y = (u32)f2b(a2 * nd) | ((u32)f2b(a3 * nd) << 16);
  o.z = (u32)f2b(a4 * nd) | ((u32)f2b(a5 * nd) << 16);
  o.w = (u32)f2b(a6 * nd) | ((u32)f2b(a7 * nd) << 16);
  *reinterpret_cast<uint4*>(aggb + (size_t)node * D + fo) = o;
}

// out[64-row tile] = aggb_tile @ W  via mfma_f32_16x16x32_bf16.
// 4 waves/block, one 16-row stripe per wave, full N=128 (8 frags), K=128 (4 steps).
// A and B staged in LDS with +8 bf16 row pad (16B) to break bank conflicts.
__global__ __launch_bounds__(256) void gemm_mfma(
    const u16* __restrict__ Ab, const u16* __restrict__ Wt,
    float* __restrict__ out, int n_rows) {
  __shared__ u16 Asl[64][D + PAD];
  __shared__ u16 Bsl[D][D + PAD];
  int tid = threadIdx.x;
  int row0 = blockIdx.x * 64;
#pragma unroll
  for (int p = 0; p < 8; ++p) {  // stage Wt (32 KB)
    int t = p * 256 + tid;
    int r = t >> 4, c = (t & 15) << 3;
    *reinterpret_cast<uint4*>(&Bsl[r][c]) =
        *reinterpret_cast<const uint4*>(Wt + r * D + c);
  }
#pragma unroll
  for (int p = 0; p < 4; ++p) {  // stage A tile (16 KB)
    int t = p * 256 + tid;
    int r = t >> 4, c = (t & 15) << 3;
    int gr = row0 + r;
    if (gr >= n_rows) gr = n_rows - 1;
    *reinterpret_cast<uint4*>(&Asl[r][c]) =
        *reinterpret_cast<const uint4*>(Ab + (size_t)gr * D + c);
  }
  __syncthreads();

  int wave = tid >> 6, lane = tid & 63;
  int lr = lane & 15, lg = lane >> 4;
  int arow = wave * 16 + lr;

  f32x4 acc[8] = {};
#pragma unroll
  for (int ks = 0; ks < 4; ++ks) {
    int k0 = ks * 32 + lg * 4;
    union { uint2 u[2]; short8 s; } pa;
    pa.u[0] = *reinterpret_cast<const uint2*>(&Asl[arow][k0]);
    pa.u[1] = *reinterpret_cast<const uint2*>(&Asl[arow][k0 + 16]);
#pragma unroll
    for (int n = 0; n < 8; ++n) {
      union { uint2 u[2]; short8 s; } pb;
      pb.u[0] = *reinterpret_cast<const uint2*>(&Bsl[n * 16 + lr][k0]);
      pb.u[1] = *reinterpret_cast<const uint2*>(&Bsl[n * 16 + lr][k0 + 16]);
      acc[n] = __builtin_amdgcn_mfma_f32_16x16x32_bf16(pa.s, pb.s, acc[n], 0, 0, 0);
    }
  }

#pragma unroll
  for (int n = 0; n < 8; ++n) {
#pragma unroll
    for (int r = 0; r < 4; ++r) {
      int gr = row0 + wave * 16 + lg * 4 + r;
      if (gr < n_rows) out[(size_t)gr * D + n * 16 + lr] = acc[n][r];
    }
  }
}

// ---------- f32 fallback path (known-good from round 2) ----------

__global__ __launch_bounds__(256) void agg_kernel(
    const int* __restrict__ edge_ptr, const int* __restrict__ src_edges,
    const float* __restrict__ src_norm, const float* __restrict__ dst_norm,
    const float* __restrict__ X, float* __restrict__ agg, int n_nodes) {
  int gid = blockIdx.x * 256 + threadIdx.x;
  int node = gid >> 5;
  if (node >= n_nodes) return;
  int fo = (gid & 31) << 2;
  int e0 = edge_ptr[node];
  int e1 = edge_ptr[node + 1];
  float ax = 0.f, ay = 0.f, az = 0.f, aw = 0.f;
  for (int e = e0; e < e1; ++e) {
    int s = src_edges[e];
    float ns = src_norm[s];
    float4 v = *reinterpret_cast<const float4*>(X + (size_t)s * D + fo);
    ax = fmaf(ns, v.x, ax); ay = fmaf(ns, v.y, ay);
    az = fmaf(ns, v.z, az); aw = fmaf(ns, v.w, aw);
  }
  float nd = dst_norm[node];
  float4 r = make_float4(ax * nd, ay * nd, az * nd, aw * nd);
  *reinterpret_cast<float4*>(agg + (size_t)node * D + fo) = r;
}

#define FMA4(acc, sv, wv)            \
  acc.x = fmaf(sv, wv.x, acc.x);     \
  acc.y = fmaf(sv, wv.y, acc.y);     \
  acc.z = fmaf(sv, wv.z, acc.z);     \
  acc.w = fmaf(sv, wv.w, acc.w);

__global__ __launch_bounds__(256) void gemm_kernel(
    float* __restrict__ io, const float* __restrict__ W, int n_rows) {
  __shared__ float Wl[D][D];
  __shared__ float Al[TM][D];
  int tid = threadIdx.x;
  for (int i = tid * 4; i < D * D; i += 1024) {
    *reinterpret_cast<float4*>(&Wl[0][0] + i) =
        *reinterpret_cast<const float4*>(W + i);
  }
  int row0 = blockIdx.x * TM;
  for (int i = tid * 4; i < TM * D; i += 1024) {
    int r = i >> 7, c = i & (D - 1);
    if (row0 + r < n_rows)
      *reinterpret_cast<float4*>(&Al[r][c]) =
          *reinterpret_cast<const float4*>(io + (size_t)(row0 + r) * D + c);
  }
  __syncthreads();

  int cg = (tid & 31) * 4;
  int rb = (tid >> 5) * 4;
  float4 acc0 = {0, 0, 0, 0}, acc1 = {0, 0, 0, 0};
  float4 acc2 = {0, 0, 0, 0}, acc3 = {0, 0, 0, 0};

#pragma unroll 4
  for (int k = 0; k < D; k += 4) {
    float4 w0 = *reinterpret_cast<const float4*>(&Wl[k + 0][cg]);
    float4 w1 = *reinterpret_cast<const float4*>(&Wl[k + 1][cg]);
    float4 w2 = *reinterpret_cast<const float4*>(&Wl[k + 2][cg]);
    float4 w3 = *reinterpret_cast<const float4*>(&Wl[k + 3][cg]);
    float4 a0 = *reinterpret_cast<const float4*>(&Al[rb + 0][k]);
    float4 a1 = *reinterpret_cast<const float4*>(&Al[rb + 1][k]);
    float4 a2 = *reinterpret_cast<const float4*>(&Al[rb + 2][k]);
    float4 a3 = *reinterpret_cast<const float4*>(&Al[rb + 3][k]);
    FMA4(acc0, a0.x, w0); FMA4(acc0, a0.y, w1); FMA4(acc0, a0.z, w2); FMA4(acc0, a0.w, w3);
    FMA4(acc1, a1.x, w0); FMA4(acc1, a1.y, w1); FMA4(acc1, a1.z, w2); FMA4(acc1, a1.w, w3);
    FMA4(acc2, a2.x, w0); FMA4(acc2, a2.y, w1); FMA4(acc2, a2.z, w2); FMA4(acc2, a2.w, w3);
    FMA4(acc3, a3.x, w0); FMA4(acc3, a3.y, w1); FMA4(acc3, a3.z, w2); FMA4(acc3, a3.w, w3);
  }

  int r0 = row0 + rb;
  if (r0 + 0 < n_rows) *reinterpret_cast<float4*>(io + (size_t)(r0 + 0) * D + cg) = acc0;
  if (r0 + 1 < n_rows) *reinterpret_cast<float4*>(io + (size_t)(r0 + 1) * D + cg) = acc1;
  if (r0 + 2 < n_rows) *reinterpret_cast<float4*>(io + (size_t)(r0 + 2) * D + cg) = acc2;
  if (r0 + 3 < n_rows) *reinterpret_cast<float4*>(io + (size_t)(r0 + 3) * D + cg) = acc3;
}

extern "C" void kernel_launch(void* const* d_in, const int* in_sizes, int n_in,
                              void* d_out, int out_size, void* d_ws, size_t ws_size,
                              hipStream_t stream) {
  const int* edge_ptr = (const int*)d_in[0];
  const int* src_edges = (const int*)d_in[1];
  const float* src_norm = (const float*)d_in[2];
  const float* dst_norm = (const float*)d_in[3];
  const float* X = (const float*)d_in[5];
  const float* W = (const float*)d_in[6];
  float* out = (float*)d_out;
  int n = in_sizes[2];  // src_norm_degs has N elements

  size_t need = (size_t)2 * n * D * sizeof(u16) + (size_t)D * D * sizeof(u16);
  if (ws_size >= need) {
    u16* Xb = (u16*)d_ws;
    u16* aggb = Xb + (size_t)n * D;
    u16* Wt = aggb + (size_t)n * D;

    int total4 = n * (D / 4);
    cvt_x<<<(total4 + 255) / 256, 256, 0, stream>>>(X, src_norm, Xb, total4);
    cvt_w<<<(D * D + 255) / 256, 256, 0, stream>>>(W, Wt);
    agg_bf16<<<(n * 16 + 255) / 256, 256, 0, stream>>>(edge_ptr, src_edges,
                                                       dst_norm, Xb, aggb, n);
    gemm_mfma<<<(n + 63) / 64, 256, 0, stream>>>(aggb, Wt, out, n);
  } else {
    int blocks1 = (n * 32 + 255) / 256;
    agg_kernel<<<blocks1, 256, 0, stream>>>(edge_ptr, src_edges, src_norm,
                                            dst_norm, X, out, n);
    int blocks2 = (n + TM - 1) / TM;
    gemm_kernel<<<blocks2, 256, 0, stream>>>(out, W, n);
  }
}